// Round 10
// baseline (645.250 us; speedup 1.0000x reference)
//
#include <hip/hip_runtime.h>
#include <math.h>

#define NNODES 50000
#define NEDGES 800000

typedef float v4f __attribute__((ext_vector_type(4)));
typedef short bf16x8 __attribute__((ext_vector_type(8)));
typedef float f32x4 __attribute__((ext_vector_type(4)));
typedef unsigned short u16x4 __attribute__((ext_vector_type(4)));
typedef _Float16 h16x4 __attribute__((ext_vector_type(4)));

// bf16 round-to-nearest-even helpers
__device__ __forceinline__ unsigned short f2bf(float f) {
    unsigned u = __float_as_uint(f);
    return (unsigned short)((u + 0x7fff + ((u >> 16) & 1)) >> 16);
}
__device__ __forceinline__ float bf2f(unsigned short h) {
    return __uint_as_float(((unsigned)h) << 16);
}

// ---------------- CSR build ----------------

__global__ void k_init_cnt(int* __restrict__ cnt) {
    int i = blockIdx.x * 256 + threadIdx.x;
    if (i < NNODES) cnt[i] = 0;
}

__global__ void k_count(const int* __restrict__ dst, int* __restrict__ cnt) {
    int e = blockIdx.x * 256 + threadIdx.x;
    if (e < NEDGES) atomicAdd(&cnt[dst[e]], 1);
}

__global__ void k_dinv(const int* __restrict__ cnt, float* __restrict__ dinv) {
    int i = blockIdx.x * 256 + threadIdx.x;
    if (i < NNODES) dinv[i] = 1.0f / sqrtf((float)cnt[i] + 1.0f);  // +1 self loop
}

// ---- hierarchical exclusive scan of cnt -> rowptr (3 passes, all parallel) ----

__global__ __launch_bounds__(256) void k_bsum(const int* __restrict__ cnt,
                                              int* __restrict__ bsum) {
    __shared__ int red[256];
    int i = blockIdx.x * 256 + threadIdx.x;
    int t = threadIdx.x;
    red[t] = (i < NNODES) ? cnt[i] : 0;
    __syncthreads();
#pragma unroll
    for (int off = 128; off > 0; off >>= 1) {
        if (t < off) red[t] += red[t + off];
        __syncthreads();
    }
    if (t == 0) bsum[blockIdx.x] = red[0];
}

__global__ __launch_bounds__(256) void k_bscan(int* __restrict__ bsum, int nblk) {
    __shared__ int s[256];
    int t = threadIdx.x;
    int v = (t < nblk) ? bsum[t] : 0;
    s[t] = v;
    __syncthreads();
#pragma unroll
    for (int off = 1; off < 256; off <<= 1) {
        int u = 0;
        if (t >= off) u = s[t - off];
        __syncthreads();
        if (t >= off) s[t] += u;
        __syncthreads();
    }
    if (t < nblk) bsum[t] = s[t] - v;   // exclusive base
}

__global__ __launch_bounds__(256) void k_rowptr(int* __restrict__ cnt,
                                                const int* __restrict__ bsum,
                                                int* __restrict__ rowptr) {
    __shared__ int s[256];
    int i = blockIdx.x * 256 + threadIdx.x;
    int t = threadIdx.x;
    int v = (i < NNODES) ? cnt[i] : 0;
    s[t] = v;
    __syncthreads();
#pragma unroll
    for (int off = 1; off < 256; off <<= 1) {
        int u = 0;
        if (t >= off) u = s[t - off];
        __syncthreads();
        if (t >= off) s[t] += u;
        __syncthreads();
    }
    if (i < NNODES) {
        rowptr[i] = bsum[blockIdx.x] + s[t] - v;   // exclusive
        cnt[i] = 0;
    }
    if (i == 0) rowptr[NNODES] = NEDGES;
}

__global__ void k_fill(const int* __restrict__ src, const int* __restrict__ dst,
                       const int* __restrict__ rowptr, int* __restrict__ cursor,
                       const float* __restrict__ dinv,
                       int* __restrict__ col, float* __restrict__ val) {
    int e = blockIdx.x * 256 + threadIdx.x;
    if (e < NEDGES) {
        int s = src[e], d = dst[e];
        int pos = rowptr[d] + atomicAdd(&cursor[d], 1);
        col[pos] = s;
        val[pos] = dinv[s] * dinv[d];
    }
}

// ---------------- W split+permute for MFMA B-fragments ----------------
// W[K][N] fp32 -> Wh/Wl bf16 in fragment order:
// slot (kt, nt, lane, j) holds W[kt*32 + (lane>>4)*8 + j][nt*16 + (lane&15)]

__global__ void k_wsplit(const float* __restrict__ W, unsigned short* __restrict__ Wh,
                         unsigned short* __restrict__ Wl, int K, int N) {
    int idx = blockIdx.x * 256 + threadIdx.x;
    if (idx >= K * N) return;
    int k = idx / N;
    int n = idx - k * N;
    float a = W[idx];
    unsigned short h = f2bf(a);
    unsigned short l = f2bf(a - bf2f(h));
    int kt = k >> 5, kr = k & 31;
    int g = kr >> 3, j = kr & 7;
    int nt = n >> 4, nc = n & 15;
    int lane = g * 16 + nc;
    size_t off = ((size_t)(kt * (N >> 4) + nt) * 64 + lane) * 8 + j;
    Wh[off] = h;
    Wl[off] = l;
}

// ---------------- fp32 tiled GEMM (encoder) ----------------
// OUTF16: write C as fp16 (RTN). All aggregation inputs are single-consumer
// intermediates -> fp16 storage halves the SpMM gather bytes AND requests.

template<int BM, int BN, int BK, int TM, int TN, bool NT, bool RELU, bool OUTF16>
__global__ __launch_bounds__(256) void k_gemm(const float* __restrict__ A,
                                              const float* __restrict__ W,
                                              const float* __restrict__ bias,
                                              float* __restrict__ C,
                                              int M, int Ncols, int K, int NB) {
    __shared__ __align__(16) float As[BK][BM];   // transposed A tile
    __shared__ __align__(16) float Ws[BK][BN];

    constexpr int CHN = TN / 4;
    constexpr int SN  = BN / CHN;
    constexpr int NTX = SN / 4;

    const int tid = threadIdx.x;
    const int tx = tid % NTX;
    const int ty = tid / NTX;
    const int bid = blockIdx.x;
    const int m0 = (bid / NB) * BM;
    const int n0 = (bid % NB) * BN;

    float acc[TM][TN];
#pragma unroll
    for (int i = 0; i < TM; ++i)
#pragma unroll
        for (int j = 0; j < TN; ++j) acc[i][j] = 0.0f;

    constexpr int AITER = (BM * BK / 4) / 256;
    constexpr int WITER = (BK * BN / 4) / 256;

    for (int k0 = 0; k0 < K; k0 += BK) {
#pragma unroll
        for (int it = 0; it < AITER; ++it) {
            int f4 = tid + it * 256;
            int row = f4 / (BK / 4);
            int kk = (f4 % (BK / 4)) * 4;
            float4 v = make_float4(0.f, 0.f, 0.f, 0.f);
            int gr = m0 + row;
            if (gr < M) v = *(const float4*)&A[(size_t)gr * K + k0 + kk];
            As[kk + 0][row] = v.x;
            As[kk + 1][row] = v.y;
            As[kk + 2][row] = v.z;
            As[kk + 3][row] = v.w;
        }
#pragma unroll
        for (int it = 0; it < WITER; ++it) {
            int f4 = tid + it * 256;
            int kk = f4 / (BN / 4);
            int nn = (f4 % (BN / 4)) * 4;
            *(float4*)&Ws[kk][nn] = *(const float4*)&W[(size_t)(k0 + kk) * Ncols + n0 + nn];
        }
        __syncthreads();

#pragma unroll
        for (int kk = 0; kk < BK; ++kk) {
            float a[TM], b[TN];
#pragma unroll
            for (int i = 0; i < TM; i += 4)
                *(float4*)&a[i] = *(const float4*)&As[kk][ty * TM + i];
#pragma unroll
            for (int c = 0; c < CHN; ++c)
                *(float4*)&b[c * 4] = *(const float4*)&Ws[kk][c * SN + tx * 4];
#pragma unroll
            for (int i = 0; i < TM; ++i)
#pragma unroll
                for (int j = 0; j < TN; ++j)
                    acc[i][j] = fmaf(a[i], b[j], acc[i][j]);
        }
        __syncthreads();
    }

#pragma unroll
    for (int i = 0; i < TM; ++i) {
        int gr = m0 + ty * TM + i;
        if (gr < M) {
#pragma unroll
            for (int c = 0; c < CHN; ++c) {
                int nb = n0 + c * SN + tx * 4;
                float4 v;
                v.x = acc[i][c * 4 + 0];
                v.y = acc[i][c * 4 + 1];
                v.z = acc[i][c * 4 + 2];
                v.w = acc[i][c * 4 + 3];
                if (bias != nullptr) {
                    v.x += bias[nb + 0];
                    v.y += bias[nb + 1];
                    v.z += bias[nb + 2];
                    v.w += bias[nb + 3];
                }
                if (RELU) {
                    v.x = fmaxf(v.x, 0.f);
                    v.y = fmaxf(v.y, 0.f);
                    v.z = fmaxf(v.z, 0.f);
                    v.w = fmaxf(v.w, 0.f);
                }
                if (OUTF16) {
                    h16x4 o;
                    o.x = (_Float16)v.x; o.y = (_Float16)v.y;
                    o.z = (_Float16)v.z; o.w = (_Float16)v.w;
                    *(h16x4*)&((_Float16*)C)[(size_t)gr * Ncols + nb] = o;
                } else if (NT) {
                    v4f nv;
                    nv.x = v.x; nv.y = v.y; nv.z = v.z; nv.w = v.w;
                    __builtin_nontemporal_store(nv, (v4f*)&C[(size_t)gr * Ncols + nb]);
                } else {
                    *(float4*)&C[(size_t)gr * Ncols + nb] = v;
                }
            }
        }
    }
}

// ---------------- MFMA bf16-split GEMM (generalized over K) ----------------
// C[M,N] = (Ah+Al)[M,K] @ (Wh+Wl)[K,N] (+bias) (+relu), fp32 accumulate.
// 3-product split: Ah*Wh + Ah*Wl + Al*Wh. No LDS; W pre-permuted, L2-hot.
// SPLIT: emit bf16 hi/lo C. OUTF16: emit fp16 C (feeds fp16-gather SpMM).
// XPIN: XCD-pinned mapping (mblk%8 == bid%8): each XCD owns a 3.2 MB A
// stripe (< 4 MB L2) -> A L2-resident. Grid: MBP*NB, MBP = MBLK padded x8.

template<int K, bool RELU, bool SPLIT, bool NT, bool XPIN, bool OUTF16>
__global__ __launch_bounds__(256) void k_mfma(
        const unsigned short* __restrict__ Ah, const unsigned short* __restrict__ Al,
        const unsigned short* __restrict__ Wh, const unsigned short* __restrict__ Wl,
        const float* __restrict__ bias, float* __restrict__ C,
        unsigned short* __restrict__ Ch, unsigned short* __restrict__ Cl,
        int M, int Ncols) {
    constexpr int KT = K / 32;
    const int lane = threadIdx.x & 63;
    const int wave = threadIdx.x >> 6;
    const int wr = wave >> 1, wc = wave & 1;
    const int l15 = lane & 15, l4 = lane >> 4;
    const int bid = blockIdx.x;
    const int MBLK = (M + 127) >> 7;
    int m0, n0;
    if (XPIN) {
        const int MBP = ((MBLK + 7) >> 3) << 3;
        const int GPX = MBP >> 3;             // m-groups per XCD stripe
        const int g = bid >> 3, q = bid & 7;  // q == XCD (bid % 8 round-robin)
        const int mblk = (g % GPX) * 8 + q;   // mblk % 8 == q: pinned stripe
        const int nb = g / GPX;
        m0 = mblk * 128;
        n0 = nb * 128;
        if (m0 >= M) return;                  // padded m-blocks idle
    } else {
        m0 = (bid % MBLK) * 128;              // m-fastest
        n0 = (bid / MBLK) * 128;
    }
    const int NT16 = Ncols >> 4;

    f32x4 acc[4][4];
#pragma unroll
    for (int i = 0; i < 4; ++i)
#pragma unroll
        for (int j = 0; j < 4; ++j) {
            f32x4 z = {0.f, 0.f, 0.f, 0.f};
            acc[i][j] = z;
        }

    int arow[4];
#pragma unroll
    for (int mf = 0; mf < 4; ++mf) {
        int r = m0 + wr * 64 + mf * 16 + l15;
        arow[mf] = r < M ? r : M - 1;         // clamp: OOB rows never stored
    }
    const int ntbase = (n0 + wc * 64) >> 4;

#pragma unroll
    for (int kt = 0; kt < KT; ++kt) {
        bf16x8 ah[4], al[4], bh[4], bl[4];
        const int ka = kt * 32 + l4 * 8;
#pragma unroll
        for (int mf = 0; mf < 4; ++mf) {
            ah[mf] = *(const bf16x8*)&Ah[(size_t)arow[mf] * K + ka];
            al[mf] = *(const bf16x8*)&Al[(size_t)arow[mf] * K + ka];
        }
#pragma unroll
        for (int nf = 0; nf < 4; ++nf) {
            size_t off = ((size_t)(kt * NT16 + ntbase + nf) * 64 + lane) * 8;
            bh[nf] = *(const bf16x8*)&Wh[off];
            bl[nf] = *(const bf16x8*)&Wl[off];
        }
#pragma unroll
        for (int mf = 0; mf < 4; ++mf)
#pragma unroll
            for (int nf = 0; nf < 4; ++nf) {
                acc[mf][nf] = __builtin_amdgcn_mfma_f32_16x16x32_bf16(ah[mf], bh[nf], acc[mf][nf], 0, 0, 0);
                acc[mf][nf] = __builtin_amdgcn_mfma_f32_16x16x32_bf16(ah[mf], bl[nf], acc[mf][nf], 0, 0, 0);
                acc[mf][nf] = __builtin_amdgcn_mfma_f32_16x16x32_bf16(al[mf], bh[nf], acc[mf][nf], 0, 0, 0);
            }
    }

    float bv[4];
#pragma unroll
    for (int nf = 0; nf < 4; ++nf)
        bv[nf] = bias ? bias[n0 + wc * 64 + nf * 16 + l15] : 0.0f;

    // C/D layout (m89-verified): col = lane&15, row = (lane>>4)*4 + reg
#pragma unroll
    for (int mf = 0; mf < 4; ++mf) {
        int gr0 = m0 + wr * 64 + mf * 16 + l4 * 4;
#pragma unroll
        for (int r = 0; r < 4; ++r) {
            int gr = gr0 + r;
            if (gr < M) {
#pragma unroll
                for (int nf = 0; nf < 4; ++nf) {
                    float v = acc[mf][nf][r] + bv[nf];
                    if (RELU) v = fmaxf(v, 0.f);
                    size_t ci = (size_t)gr * Ncols + n0 + wc * 64 + nf * 16 + l15;
                    if (SPLIT) {
                        unsigned short h = f2bf(v);
                        Ch[ci] = h;
                        Cl[ci] = f2bf(v - bf2f(h));
                    } else if (OUTF16) {
                        ((_Float16*)C)[ci] = (_Float16)v;
                    } else if (NT) {
                        __builtin_nontemporal_store(v, &C[ci]);
                    } else {
                        C[ci] = v;
                    }
                }
            }
        }
    }
}

// ---------------- CSR SpMM (row-major, fp16 gathers, masked batches) ---------
// out[row] = sum_e H[col[e]]*val[e] + H[row]*dinv^2 (+bias) (+relu)
// F16: H stored fp16 (half the gather bytes/requests). fp32 accumulate.
// Edge loop: ceil(deg/8) MASKED 8-deep batches. The old scalar tail was up to
// 7 SERIALIZED full-latency gathers (col->gather->fmaf dep chain, ~500cy each;
// deg%8 avg 3.5 ~ half the row's critical path at Poisson(16) degree).
// Pad slots: s=0 (select-after-load, no OOB index), w=0.0f -> fmaf no-op;
// row-0 gather line is L2-hot chip-wide. Real-edge fmaf chain order is
// UNCHANGED -> bitwise-identical output.
// SPLIT: emit bf16 hi/lo (feeds a downstream MFMA GEMM) instead of fp32.

template<int CH, bool RELU, bool HB, bool SPLIT, bool F16>
__global__ __launch_bounds__(256) void k_spmm(const void* __restrict__ Hv,
                                              const float* __restrict__ dinv,
                                              const int* __restrict__ rowptr,
                                              const int* __restrict__ col,
                                              const float* __restrict__ val,
                                              const float* __restrict__ bias,
                                              float* __restrict__ out,
                                              unsigned short* __restrict__ Oh,
                                              unsigned short* __restrict__ Ol) {
    constexpr int CV = CH / 4;
    const float* Hf = (const float*)Hv;
    const _Float16* Hh = (const _Float16*)Hv;
    int t = blockIdx.x * 256 + threadIdx.x;
    int row = t / CV;
    if (row >= NNODES) return;
    int c = (t % CV) * 4;

    auto load4 = [&](size_t idx) -> float4 {
        if constexpr (F16) {
            h16x4 x = *(const h16x4*)&Hh[idx];
            float4 r;
            r.x = (float)x.x; r.y = (float)x.y; r.z = (float)x.z; r.w = (float)x.w;
            return r;
        } else {
            return *(const float4*)&Hf[idx];
        }
    };

    float dv = dinv[row];
    float s2 = dv * dv;
    float4 h = load4((size_t)row * CH + c);
    float ax, ay, az, aw;
    if (HB) {
        float4 b = *(const float4*)&bias[c];
        ax = fmaf(h.x, s2, b.x);
        ay = fmaf(h.y, s2, b.y);
        az = fmaf(h.z, s2, b.z);
        aw = fmaf(h.w, s2, b.w);
    } else {
        ax = h.x * s2;
        ay = h.y * s2;
        az = h.z * s2;
        aw = h.w * s2;
    }

    const int e0 = rowptr[row], e1 = rowptr[row + 1];
    for (int e = e0; e < e1; e += 8) {
        int s[8];
        float w[8];
#pragma unroll
        for (int u = 0; u < 8; ++u) {
            int idx = e + u;                 // col/val allocs padded +32 elems:
            bool ok = idx < e1;              // speculative load stays in-bounds
            s[u] = ok ? col[idx] : 0;        // select AFTER load -> s in [0,N)
            w[u] = ok ? val[idx] : 0.0f;     // pad fmaf(h,0,acc) is exact no-op
        }
        float4 hv[8];
#pragma unroll
        for (int u = 0; u < 8; ++u)
            hv[u] = load4((size_t)s[u] * CH + c);
#pragma unroll
        for (int u = 0; u < 8; ++u) {
            ax = fmaf(hv[u].x, w[u], ax);
            ay = fmaf(hv[u].y, w[u], ay);
            az = fmaf(hv[u].z, w[u], az);
            aw = fmaf(hv[u].w, w[u], aw);
        }
    }
    if (RELU) {
        ax = fmaxf(ax, 0.f);
        ay = fmaxf(ay, 0.f);
        az = fmaxf(az, 0.f);
        aw = fmaxf(aw, 0.f);
    }
    if (SPLIT) {
        u16x4 hvv, lvv;
        hvv.x = f2bf(ax); lvv.x = f2bf(ax - bf2f(hvv.x));
        hvv.y = f2bf(ay); lvv.y = f2bf(ay - bf2f(hvv.y));
        hvv.z = f2bf(az); lvv.z = f2bf(az - bf2f(hvv.z));
        hvv.w = f2bf(aw); lvv.w = f2bf(aw - bf2f(hvv.w));
        *(u16x4*)&Oh[(size_t)row * CH + c] = hvv;
        *(u16x4*)&Ol[(size_t)row * CH + c] = lvv;
    } else {
        float4 o;
        o.x = ax; o.y = ay; o.z = az; o.w = aw;
        *(float4*)&out[(size_t)row * CH + c] = o;
    }
}

// ---------------- launcher ----------------

extern "C" void kernel_launch(void* const* d_in, const int* in_sizes, int n_in,
                              void* d_out, int out_size, void* d_ws, size_t ws_size,
                              hipStream_t stream) {
    const float* x   = (const float*)d_in[0];
    const int*   ei  = (const int*)d_in[1];
    const float* eW1 = (const float*)d_in[2];
    const float* eb1 = (const float*)d_in[3];
    const float* eW2 = (const float*)d_in[4];
    const float* eb2 = (const float*)d_in[5];
    const float* eWf = (const float*)d_in[6];
    const float* ebf = (const float*)d_in[7];
    const float* dW1 = (const float*)d_in[8];
    const float* db1 = (const float*)d_in[9];
    const float* dW2 = (const float*)d_in[10];
    const float* db2 = (const float*)d_in[11];
    const float* dWf = (const float*)d_in[12];
    const float* dbf = (const float*)d_in[13];
    float* out = (float*)d_out;

    char* ws = (char*)d_ws;
    size_t off = 0;
    auto alloc = [&](size_t bytes) { size_t r = off; off += (bytes + 255) & ~(size_t)255; return r; };
    float* dinv   = (float*)(ws + alloc((size_t)NNODES * 4));
    int*   cnt    = (int*)  (ws + alloc((size_t)NNODES * 4));
    int*   rowptr = (int*)  (ws + alloc((size_t)(NNODES + 1) * 4));
    int*   bsum   = (int*)  (ws + alloc((size_t)256 * 4));
    int*   col    = (int*)  (ws + alloc((size_t)(NEDGES + 32) * 4));  // +32: masked-batch pad
    float* val    = (float*)(ws + alloc((size_t)(NEDGES + 32) * 4));  // +32: masked-batch pad
    float* B1     = (float*)(ws + alloc((size_t)NNODES * 256 * 4));
    unsigned short* Wfh = (unsigned short*)(ws + alloc((size_t)128 * 1024 * 2));  // dWf split
    unsigned short* Wfl = (unsigned short*)(ws + alloc((size_t)128 * 1024 * 2));
    unsigned short* W1h = (unsigned short*)(ws + alloc((size_t)64 * 256 * 2));    // dW1 split
    unsigned short* W1l = (unsigned short*)(ws + alloc((size_t)64 * 256 * 2));
    unsigned short* W2h = (unsigned short*)(ws + alloc((size_t)256 * 128 * 2));   // dW2 split
    unsigned short* W2l = (unsigned short*)(ws + alloc((size_t)256 * 128 * 2));

    // Aliases into B1 (51.2 MB) and B2 (= front of d_out, <=51.2 MB used):
    // timeline guarantees no overlap of live ranges (see per-call comments).
    float* B2 = out;
    unsigned short* Gh  = (unsigned short*)B2;                                    // agg(Z) split, 6.4 MB
    unsigned short* Gl  = (unsigned short*)((char*)B2 + (size_t)NNODES * 64 * 2);
    unsigned short* A3h = (unsigned short*)B1;                                    // A3 split, 25.6 MB each
    unsigned short* A3l = (unsigned short*)((char*)B1 + (size_t)NNODES * 256 * 2);
    unsigned short* Ah  = (unsigned short*)B1;                                    // A4 split, 12.8 MB each
    unsigned short* Al  = (unsigned short*)((char*)B1 + (size_t)NNODES * 128 * 2);

    const int* src = ei;
    const int* dst = ei + NEDGES;

    const int gN = (NNODES + 255) / 256;   // 196
    const int gE = (NEDGES + 255) / 256;

    k_init_cnt<<<gN, 256, 0, stream>>>(cnt);
    k_count<<<gE, 256, 0, stream>>>(dst, cnt);
    k_dinv<<<gN, 256, 0, stream>>>(cnt, dinv);
    k_bsum<<<gN, 256, 0, stream>>>(cnt, bsum);
    k_bscan<<<1, 256, 0, stream>>>(bsum, gN);
    k_rowptr<<<gN, 256, 0, stream>>>(cnt, bsum, rowptr);
    k_fill<<<gE, 256, 0, stream>>>(src, dst, rowptr, cnt, dinv, col, val);
    // weight splits for the MFMA decoder (no pipeline deps; tiny)
    k_wsplit<<<(128 * 1024 + 255) / 256, 256, 0, stream>>>(dWf, Wfh, Wfl, 128, 1024);
    k_wsplit<<<(64 * 256 + 255) / 256, 256, 0, stream>>>(dW1, W1h, W1l, 64, 256);
    k_wsplit<<<(256 * 128 + 255) / 256, 256, 0, stream>>>(dW2, W2h, W2l, 256, 128);

    const int MB = (NNODES + 127) / 128;     // 391 row-blocks
    const int MBP = ((MB + 7) / 8) * 8;      // 392, padded for XCD-pinned grid

    // ---- Encoder (fp32 GEMMs; aggregation inputs stored fp16) ----
    // H1 = x @ eW1 -> B1 as fp16 [50000,128] (12.8 MB; sole consumer = A1 agg)
    k_gemm<128,128,16,8,8,false,false,true><<<MB, 256, 0, stream>>>(x, eW1, nullptr, B1, NNODES, 128, 128, 1);
    // A1 = relu(agg(H1) + eb1) -> B2 fp32   (fp16 gathers: 205 MB vs 410)
    k_spmm<128,true,true,false,true><<<(NNODES * 32 + 255) / 256, 256, 0, stream>>>(B1, dinv, rowptr, col, val, eb1, B2, nullptr, nullptr);
    // H2 = A1 @ eW2 -> B1 as fp16 [50000,64]
    k_gemm<128,64,16,8,4,false,false,true><<<MB, 256, 0, stream>>>(B2, eW2, nullptr, B1, NNODES, 64, 128, 1);
    // A2 = agg(H2) + eb2 -> B2 fp32         (fp16 gathers)
    k_spmm<64,false,true,false,true><<<(NNODES * 16 + 255) / 256, 256, 0, stream>>>(B1, dinv, rowptr, col, val, eb2, B2, nullptr, nullptr);
    // Z = A2 @ eWf + ebf -> B1 as fp16 [50000,64]
    k_gemm<128,64,16,8,4,false,false,true><<<MB, 256, 0, stream>>>(B2, eWf, ebf, B1, NNODES, 64, 64, 1);

    // ---- Decoder (MFMA bf16-split path) ----
    // G = agg(Z), bf16-split -> Gh/Gl in B2 (A2 dead; fp16 gathers)
    k_spmm<64,false,false,true,true><<<(NNODES * 16 + 255) / 256, 256, 0, stream>>>(B1, dinv, rowptr, col, val, nullptr, nullptr, Gh, Gl);
    // A3 = relu(G @ dW1 + db1), bf16-split -> A3h/A3l in B1 (Z dead)  [K=64, N=256]
    k_mfma<64,true,true,false,false,false><<<MB * 2, 256, 0, stream>>>(Gh, Gl, W1h, W1l, db1, nullptr, A3h, A3l, NNODES, 256);
    // H4 = A3 @ dW2 -> B2 as fp16 [50000,128] (G dead)  [K=256, N=128]
    k_mfma<256,false,false,false,false,true><<<MB, 256, 0, stream>>>(A3h, A3l, W2h, W2l, nullptr, B2, nullptr, nullptr, NNODES, 128);
    // A4 = agg(H4) + db2, bf16-split -> Ah/Al in B1 (A3 dead; fp16 gathers)
    k_spmm<128,false,true,true,true><<<(NNODES * 32 + 255) / 256, 256, 0, stream>>>(B2, dinv, rowptr, col, val, db2, nullptr, Ah, Al);
    // x_hat = A4 @ dWf + dbf -> d_out  [K=128, N=1024]  (XCD-pinned grid,
    // nontemporal stores; B2 region of out fully overwritten after last read)
    k_mfma<128,false,false,true,true,false><<<MBP * 8, 256, 0, stream>>>(Ah, Al, Wfh, Wfl, dbf, out, nullptr, nullptr, NNODES, 1024);
}

// Round 11
// 628.157 us; speedup vs baseline: 1.0272x; 1.0272x over previous
//
#include <hip/hip_runtime.h>
#include <math.h>

#define NNODES 50000
#define NEDGES 800000

typedef float v4f __attribute__((ext_vector_type(4)));
typedef short bf16x8 __attribute__((ext_vector_type(8)));
typedef float f32x4 __attribute__((ext_vector_type(4)));
typedef unsigned short u16x4 __attribute__((ext_vector_type(4)));
typedef _Float16 h16x4 __attribute__((ext_vector_type(4)));
typedef _Float16 h16x8 __attribute__((ext_vector_type(8)));

// bf16 round-to-nearest-even helpers
__device__ __forceinline__ unsigned short f2bf(float f) {
    unsigned u = __float_as_uint(f);
    return (unsigned short)((u + 0x7fff + ((u >> 16) & 1)) >> 16);
}
__device__ __forceinline__ float bf2f(unsigned short h) {
    return __uint_as_float(((unsigned)h) << 16);
}

// ---------------- CSR build ----------------

__global__ void k_init_cnt(int* __restrict__ cnt) {
    int i = blockIdx.x * 256 + threadIdx.x;
    if (i < NNODES) cnt[i] = 0;
}

__global__ void k_count(const int* __restrict__ dst, int* __restrict__ cnt) {
    int e = blockIdx.x * 256 + threadIdx.x;
    if (e < NEDGES) atomicAdd(&cnt[dst[e]], 1);
}

__global__ void k_dinv(const int* __restrict__ cnt, float* __restrict__ dinv) {
    int i = blockIdx.x * 256 + threadIdx.x;
    if (i < NNODES) dinv[i] = 1.0f / sqrtf((float)cnt[i] + 1.0f);  // +1 self loop
}

// ---- hierarchical exclusive scan of cnt -> rowptr (3 passes, all parallel) ----

__global__ __launch_bounds__(256) void k_bsum(const int* __restrict__ cnt,
                                              int* __restrict__ bsum) {
    __shared__ int red[256];
    int i = blockIdx.x * 256 + threadIdx.x;
    int t = threadIdx.x;
    red[t] = (i < NNODES) ? cnt[i] : 0;
    __syncthreads();
#pragma unroll
    for (int off = 128; off > 0; off >>= 1) {
        if (t < off) red[t] += red[t + off];
        __syncthreads();
    }
    if (t == 0) bsum[blockIdx.x] = red[0];
}

__global__ __launch_bounds__(256) void k_bscan(int* __restrict__ bsum, int nblk) {
    __shared__ int s[256];
    int t = threadIdx.x;
    int v = (t < nblk) ? bsum[t] : 0;
    s[t] = v;
    __syncthreads();
#pragma unroll
    for (int off = 1; off < 256; off <<= 1) {
        int u = 0;
        if (t >= off) u = s[t - off];
        __syncthreads();
        if (t >= off) s[t] += u;
        __syncthreads();
    }
    if (t < nblk) bsum[t] = s[t] - v;   // exclusive base
}

__global__ __launch_bounds__(256) void k_rowptr(int* __restrict__ cnt,
                                                const int* __restrict__ bsum,
                                                int* __restrict__ rowptr) {
    __shared__ int s[256];
    int i = blockIdx.x * 256 + threadIdx.x;
    int t = threadIdx.x;
    int v = (i < NNODES) ? cnt[i] : 0;
    s[t] = v;
    __syncthreads();
#pragma unroll
    for (int off = 1; off < 256; off <<= 1) {
        int u = 0;
        if (t >= off) u = s[t - off];
        __syncthreads();
        if (t >= off) s[t] += u;
        __syncthreads();
    }
    if (i < NNODES) {
        rowptr[i] = bsum[blockIdx.x] + s[t] - v;   // exclusive
        cnt[i] = 0;
    }
    if (i == 0) rowptr[NNODES] = NEDGES;
}

__global__ void k_fill(const int* __restrict__ src, const int* __restrict__ dst,
                       const int* __restrict__ rowptr, int* __restrict__ cursor,
                       const float* __restrict__ dinv,
                       int* __restrict__ col, float* __restrict__ val) {
    int e = blockIdx.x * 256 + threadIdx.x;
    if (e < NEDGES) {
        int s = src[e], d = dst[e];
        int pos = rowptr[d] + atomicAdd(&cursor[d], 1);
        col[pos] = s;
        val[pos] = dinv[s] * dinv[d];
    }
}

// ---------------- W split+permute for MFMA B-fragments ----------------
// W[K][N] fp32 -> Wh/Wl bf16 in fragment order:
// slot (kt, nt, lane, j) holds W[kt*32 + (lane>>4)*8 + j][nt*16 + (lane&15)]

__global__ void k_wsplit(const float* __restrict__ W, unsigned short* __restrict__ Wh,
                         unsigned short* __restrict__ Wl, int K, int N) {
    int idx = blockIdx.x * 256 + threadIdx.x;
    if (idx >= K * N) return;
    int k = idx / N;
    int n = idx - k * N;
    float a = W[idx];
    unsigned short h = f2bf(a);
    unsigned short l = f2bf(a - bf2f(h));
    int kt = k >> 5, kr = k & 31;
    int g = kr >> 3, j = kr & 7;
    int nt = n >> 4, nc = n & 15;
    int lane = g * 16 + nc;
    size_t off = ((size_t)(kt * (N >> 4) + nt) * 64 + lane) * 8 + j;
    Wh[off] = h;
    Wl[off] = l;
}

// ---------------- fp32 tiled GEMM (encoder) ----------------
// OUTF16: write C as fp16 (RTN). All aggregation inputs are single-consumer
// intermediates -> fp16 storage halves the SpMM gather bytes AND requests.

template<int BM, int BN, int BK, int TM, int TN, bool NT, bool RELU, bool OUTF16>
__global__ __launch_bounds__(256) void k_gemm(const float* __restrict__ A,
                                              const float* __restrict__ W,
                                              const float* __restrict__ bias,
                                              float* __restrict__ C,
                                              int M, int Ncols, int K, int NB) {
    __shared__ __align__(16) float As[BK][BM];   // transposed A tile
    __shared__ __align__(16) float Ws[BK][BN];

    constexpr int CHN = TN / 4;
    constexpr int SN  = BN / CHN;
    constexpr int NTX = SN / 4;

    const int tid = threadIdx.x;
    const int tx = tid % NTX;
    const int ty = tid / NTX;
    const int bid = blockIdx.x;
    const int m0 = (bid / NB) * BM;
    const int n0 = (bid % NB) * BN;

    float acc[TM][TN];
#pragma unroll
    for (int i = 0; i < TM; ++i)
#pragma unroll
        for (int j = 0; j < TN; ++j) acc[i][j] = 0.0f;

    constexpr int AITER = (BM * BK / 4) / 256;
    constexpr int WITER = (BK * BN / 4) / 256;

    for (int k0 = 0; k0 < K; k0 += BK) {
#pragma unroll
        for (int it = 0; it < AITER; ++it) {
            int f4 = tid + it * 256;
            int row = f4 / (BK / 4);
            int kk = (f4 % (BK / 4)) * 4;
            float4 v = make_float4(0.f, 0.f, 0.f, 0.f);
            int gr = m0 + row;
            if (gr < M) v = *(const float4*)&A[(size_t)gr * K + k0 + kk];
            As[kk + 0][row] = v.x;
            As[kk + 1][row] = v.y;
            As[kk + 2][row] = v.z;
            As[kk + 3][row] = v.w;
        }
#pragma unroll
        for (int it = 0; it < WITER; ++it) {
            int f4 = tid + it * 256;
            int kk = f4 / (BN / 4);
            int nn = (f4 % (BN / 4)) * 4;
            *(float4*)&Ws[kk][nn] = *(const float4*)&W[(size_t)(k0 + kk) * Ncols + n0 + nn];
        }
        __syncthreads();

#pragma unroll
        for (int kk = 0; kk < BK; ++kk) {
            float a[TM], b[TN];
#pragma unroll
            for (int i = 0; i < TM; i += 4)
                *(float4*)&a[i] = *(const float4*)&As[kk][ty * TM + i];
#pragma unroll
            for (int c = 0; c < CHN; ++c)
                *(float4*)&b[c * 4] = *(const float4*)&Ws[kk][c * SN + tx * 4];
#pragma unroll
            for (int i = 0; i < TM; ++i)
#pragma unroll
                for (int j = 0; j < TN; ++j)
                    acc[i][j] = fmaf(a[i], b[j], acc[i][j]);
        }
        __syncthreads();
    }

#pragma unroll
    for (int i = 0; i < TM; ++i) {
        int gr = m0 + ty * TM + i;
        if (gr < M) {
#pragma unroll
            for (int c = 0; c < CHN; ++c) {
                int nb = n0 + c * SN + tx * 4;
                float4 v;
                v.x = acc[i][c * 4 + 0];
                v.y = acc[i][c * 4 + 1];
                v.z = acc[i][c * 4 + 2];
                v.w = acc[i][c * 4 + 3];
                if (bias != nullptr) {
                    v.x += bias[nb + 0];
                    v.y += bias[nb + 1];
                    v.z += bias[nb + 2];
                    v.w += bias[nb + 3];
                }
                if (RELU) {
                    v.x = fmaxf(v.x, 0.f);
                    v.y = fmaxf(v.y, 0.f);
                    v.z = fmaxf(v.z, 0.f);
                    v.w = fmaxf(v.w, 0.f);
                }
                if (OUTF16) {
                    h16x4 o;
                    o.x = (_Float16)v.x; o.y = (_Float16)v.y;
                    o.z = (_Float16)v.z; o.w = (_Float16)v.w;
                    *(h16x4*)&((_Float16*)C)[(size_t)gr * Ncols + nb] = o;
                } else if (NT) {
                    v4f nv;
                    nv.x = v.x; nv.y = v.y; nv.z = v.z; nv.w = v.w;
                    __builtin_nontemporal_store(nv, (v4f*)&C[(size_t)gr * Ncols + nb]);
                } else {
                    *(float4*)&C[(size_t)gr * Ncols + nb] = v;
                }
            }
        }
    }
}

// ---------------- MFMA bf16-split GEMM (generalized over K) ----------------
// C[M,N] = (Ah+Al)[M,K] @ (Wh+Wl)[K,N] (+bias) (+relu), fp32 accumulate.
// 3-product split: Ah*Wh + Ah*Wl + Al*Wh. No LDS; W pre-permuted, L2-hot.
// SPLIT: emit bf16 hi/lo C. OUTF16: emit fp16 C (feeds fp16-gather SpMM).
// XPIN: XCD-pinned mapping (mblk%8 == bid%8): each XCD owns a 3.2 MB A
// stripe (< 4 MB L2) -> A L2-resident. Grid: MBP*NB, MBP = MBLK padded x8.

template<int K, bool RELU, bool SPLIT, bool NT, bool XPIN, bool OUTF16>
__global__ __launch_bounds__(256) void k_mfma(
        const unsigned short* __restrict__ Ah, const unsigned short* __restrict__ Al,
        const unsigned short* __restrict__ Wh, const unsigned short* __restrict__ Wl,
        const float* __restrict__ bias, float* __restrict__ C,
        unsigned short* __restrict__ Ch, unsigned short* __restrict__ Cl,
        int M, int Ncols) {
    constexpr int KT = K / 32;
    const int lane = threadIdx.x & 63;
    const int wave = threadIdx.x >> 6;
    const int wr = wave >> 1, wc = wave & 1;
    const int l15 = lane & 15, l4 = lane >> 4;
    const int bid = blockIdx.x;
    const int MBLK = (M + 127) >> 7;
    int m0, n0;
    if (XPIN) {
        const int MBP = ((MBLK + 7) >> 3) << 3;
        const int GPX = MBP >> 3;             // m-groups per XCD stripe
        const int g = bid >> 3, q = bid & 7;  // q == XCD (bid % 8 round-robin)
        const int mblk = (g % GPX) * 8 + q;   // mblk % 8 == q: pinned stripe
        const int nb = g / GPX;
        m0 = mblk * 128;
        n0 = nb * 128;
        if (m0 >= M) return;                  // padded m-blocks idle
    } else {
        m0 = (bid % MBLK) * 128;              // m-fastest
        n0 = (bid / MBLK) * 128;
    }
    const int NT16 = Ncols >> 4;

    f32x4 acc[4][4];
#pragma unroll
    for (int i = 0; i < 4; ++i)
#pragma unroll
        for (int j = 0; j < 4; ++j) {
            f32x4 z = {0.f, 0.f, 0.f, 0.f};
            acc[i][j] = z;
        }

    int arow[4];
#pragma unroll
    for (int mf = 0; mf < 4; ++mf) {
        int r = m0 + wr * 64 + mf * 16 + l15;
        arow[mf] = r < M ? r : M - 1;         // clamp: OOB rows never stored
    }
    const int ntbase = (n0 + wc * 64) >> 4;

#pragma unroll
    for (int kt = 0; kt < KT; ++kt) {
        bf16x8 ah[4], al[4], bh[4], bl[4];
        const int ka = kt * 32 + l4 * 8;
#pragma unroll
        for (int mf = 0; mf < 4; ++mf) {
            ah[mf] = *(const bf16x8*)&Ah[(size_t)arow[mf] * K + ka];
            al[mf] = *(const bf16x8*)&Al[(size_t)arow[mf] * K + ka];
        }
#pragma unroll
        for (int nf = 0; nf < 4; ++nf) {
            size_t off = ((size_t)(kt * NT16 + ntbase + nf) * 64 + lane) * 8;
            bh[nf] = *(const bf16x8*)&Wh[off];
            bl[nf] = *(const bf16x8*)&Wl[off];
        }
#pragma unroll
        for (int mf = 0; mf < 4; ++mf)
#pragma unroll
            for (int nf = 0; nf < 4; ++nf) {
                acc[mf][nf] = __builtin_amdgcn_mfma_f32_16x16x32_bf16(ah[mf], bh[nf], acc[mf][nf], 0, 0, 0);
                acc[mf][nf] = __builtin_amdgcn_mfma_f32_16x16x32_bf16(ah[mf], bl[nf], acc[mf][nf], 0, 0, 0);
                acc[mf][nf] = __builtin_amdgcn_mfma_f32_16x16x32_bf16(al[mf], bh[nf], acc[mf][nf], 0, 0, 0);
            }
    }

    float bv[4];
#pragma unroll
    for (int nf = 0; nf < 4; ++nf)
        bv[nf] = bias ? bias[n0 + wc * 64 + nf * 16 + l15] : 0.0f;

    // C/D layout (m89-verified): col = lane&15, row = (lane>>4)*4 + reg
#pragma unroll
    for (int mf = 0; mf < 4; ++mf) {
        int gr0 = m0 + wr * 64 + mf * 16 + l4 * 4;
#pragma unroll
        for (int r = 0; r < 4; ++r) {
            int gr = gr0 + r;
            if (gr < M) {
#pragma unroll
                for (int nf = 0; nf < 4; ++nf) {
                    float v = acc[mf][nf][r] + bv[nf];
                    if (RELU) v = fmaxf(v, 0.f);
                    size_t ci = (size_t)gr * Ncols + n0 + wc * 64 + nf * 16 + l15;
                    if (SPLIT) {
                        unsigned short h = f2bf(v);
                        Ch[ci] = h;
                        Cl[ci] = f2bf(v - bf2f(h));
                    } else if (OUTF16) {
                        ((_Float16*)C)[ci] = (_Float16)v;
                    } else if (NT) {
                        __builtin_nontemporal_store(v, &C[ci]);
                    } else {
                        C[ci] = v;
                    }
                }
            }
        }
    }
}

// ---------------- CSR SpMM (fp16 gathers, 16B/lane) ----------------
// out[row] = sum_e H[col[e]]*val[e] + H[row]*dinv^2 (+bias) (+relu)
// H is fp16; each lane loads h16x8 = 16B -> CV = CH/8 lanes per row.
// Per-edge instruction cost decomposition (r9/r10 fits): ~2/3 of each agg
// layer is width-invariant per-edge instruction/dep cost, not bytes. 16B
// lanes halve gather instructions + addr work per edge (same lines touched).
// Scalar tail RESTORED (r10's masked batches = +25% issued gathers, -15us).
// Per-channel fmaf chain order identical -> bitwise-identical output.
// SPLIT: emit bf16 hi/lo (feeds a downstream MFMA GEMM) instead of fp32.

template<int CH, bool RELU, bool HB, bool SPLIT>
__global__ __launch_bounds__(256) void k_spmm(const _Float16* __restrict__ H,
                                              const float* __restrict__ dinv,
                                              const int* __restrict__ rowptr,
                                              const int* __restrict__ col,
                                              const float* __restrict__ val,
                                              const float* __restrict__ bias,
                                              float* __restrict__ out,
                                              unsigned short* __restrict__ Oh,
                                              unsigned short* __restrict__ Ol) {
    constexpr int CV = CH / 8;            // lanes per row (16B fp16 loads)
    int t = blockIdx.x * 256 + threadIdx.x;
    int row = t / CV;
    if (row >= NNODES) return;
    int c = (t % CV) * 8;

    float dv = dinv[row];
    float s2 = dv * dv;
    h16x8 h = *(const h16x8*)&H[(size_t)row * CH + c];
    float acc[8];
    if (HB) {
        float4 b0 = *(const float4*)&bias[c];
        float4 b1 = *(const float4*)&bias[c + 4];
        acc[0] = fmaf((float)h[0], s2, b0.x);
        acc[1] = fmaf((float)h[1], s2, b0.y);
        acc[2] = fmaf((float)h[2], s2, b0.z);
        acc[3] = fmaf((float)h[3], s2, b0.w);
        acc[4] = fmaf((float)h[4], s2, b1.x);
        acc[5] = fmaf((float)h[5], s2, b1.y);
        acc[6] = fmaf((float)h[6], s2, b1.z);
        acc[7] = fmaf((float)h[7], s2, b1.w);
    } else {
#pragma unroll
        for (int j = 0; j < 8; ++j) acc[j] = (float)h[j] * s2;
    }

    const int e0 = rowptr[row], e1 = rowptr[row + 1];
    int e = e0;
    for (; e + 8 <= e1; e += 8) {
        int s[8];
        float w[8];
#pragma unroll
        for (int u = 0; u < 8; ++u) { s[u] = col[e + u]; w[u] = val[e + u]; }
        h16x8 hv[8];
#pragma unroll
        for (int u = 0; u < 8; ++u)
            hv[u] = *(const h16x8*)&H[(size_t)s[u] * CH + c];
#pragma unroll
        for (int u = 0; u < 8; ++u)
#pragma unroll
            for (int j = 0; j < 8; ++j)
                acc[j] = fmaf((float)hv[u][j], w[u], acc[j]);
    }
    for (; e < e1; ++e) {
        int sidx = col[e];
        float w = val[e];
        h16x8 hv = *(const h16x8*)&H[(size_t)sidx * CH + c];
#pragma unroll
        for (int j = 0; j < 8; ++j)
            acc[j] = fmaf((float)hv[j], w, acc[j]);
    }
    if (RELU) {
#pragma unroll
        for (int j = 0; j < 8; ++j) acc[j] = fmaxf(acc[j], 0.f);
    }
    if (SPLIT) {
        u16x4 h0, h1, l0, l1;
        unsigned short hs;
        hs = f2bf(acc[0]); h0.x = hs; l0.x = f2bf(acc[0] - bf2f(hs));
        hs = f2bf(acc[1]); h0.y = hs; l0.y = f2bf(acc[1] - bf2f(hs));
        hs = f2bf(acc[2]); h0.z = hs; l0.z = f2bf(acc[2] - bf2f(hs));
        hs = f2bf(acc[3]); h0.w = hs; l0.w = f2bf(acc[3] - bf2f(hs));
        hs = f2bf(acc[4]); h1.x = hs; l1.x = f2bf(acc[4] - bf2f(hs));
        hs = f2bf(acc[5]); h1.y = hs; l1.y = f2bf(acc[5] - bf2f(hs));
        hs = f2bf(acc[6]); h1.z = hs; l1.z = f2bf(acc[6] - bf2f(hs));
        hs = f2bf(acc[7]); h1.w = hs; l1.w = f2bf(acc[7] - bf2f(hs));
        *(u16x4*)&Oh[(size_t)row * CH + c] = h0;
        *(u16x4*)&Oh[(size_t)row * CH + c + 4] = h1;
        *(u16x4*)&Ol[(size_t)row * CH + c] = l0;
        *(u16x4*)&Ol[(size_t)row * CH + c + 4] = l1;
    } else {
        float4 o0, o1;
        o0.x = acc[0]; o0.y = acc[1]; o0.z = acc[2]; o0.w = acc[3];
        o1.x = acc[4]; o1.y = acc[5]; o1.z = acc[6]; o1.w = acc[7];
        *(float4*)&out[(size_t)row * CH + c] = o0;
        *(float4*)&out[(size_t)row * CH + c + 4] = o1;
    }
}

// ---------------- launcher ----------------

extern "C" void kernel_launch(void* const* d_in, const int* in_sizes, int n_in,
                              void* d_out, int out_size, void* d_ws, size_t ws_size,
                              hipStream_t stream) {
    const float* x   = (const float*)d_in[0];
    const int*   ei  = (const int*)d_in[1];
    const float* eW1 = (const float*)d_in[2];
    const float* eb1 = (const float*)d_in[3];
    const float* eW2 = (const float*)d_in[4];
    const float* eb2 = (const float*)d_in[5];
    const float* eWf = (const float*)d_in[6];
    const float* ebf = (const float*)d_in[7];
    const float* dW1 = (const float*)d_in[8];
    const float* db1 = (const float*)d_in[9];
    const float* dW2 = (const float*)d_in[10];
    const float* db2 = (const float*)d_in[11];
    const float* dWf = (const float*)d_in[12];
    const float* dbf = (const float*)d_in[13];
    float* out = (float*)d_out;

    char* ws = (char*)d_ws;
    size_t off = 0;
    auto alloc = [&](size_t bytes) { size_t r = off; off += (bytes + 255) & ~(size_t)255; return r; };
    float* dinv   = (float*)(ws + alloc((size_t)NNODES * 4));
    int*   cnt    = (int*)  (ws + alloc((size_t)NNODES * 4));
    int*   rowptr = (int*)  (ws + alloc((size_t)(NNODES + 1) * 4));
    int*   bsum   = (int*)  (ws + alloc((size_t)256 * 4));
    int*   col    = (int*)  (ws + alloc((size_t)(NEDGES + 32) * 4));
    float* val    = (float*)(ws + alloc((size_t)(NEDGES + 32) * 4));
    float* B1     = (float*)(ws + alloc((size_t)NNODES * 256 * 4));
    unsigned short* Wfh = (unsigned short*)(ws + alloc((size_t)128 * 1024 * 2));  // dWf split
    unsigned short* Wfl = (unsigned short*)(ws + alloc((size_t)128 * 1024 * 2));
    unsigned short* W1h = (unsigned short*)(ws + alloc((size_t)64 * 256 * 2));    // dW1 split
    unsigned short* W1l = (unsigned short*)(ws + alloc((size_t)64 * 256 * 2));
    unsigned short* W2h = (unsigned short*)(ws + alloc((size_t)256 * 128 * 2));   // dW2 split
    unsigned short* W2l = (unsigned short*)(ws + alloc((size_t)256 * 128 * 2));

    // Aliases into B1 (51.2 MB) and B2 (= front of d_out, <=51.2 MB used):
    // timeline guarantees no overlap of live ranges (see per-call comments).
    float* B2 = out;
    unsigned short* Gh  = (unsigned short*)B2;                                    // agg(Z) split, 6.4 MB
    unsigned short* Gl  = (unsigned short*)((char*)B2 + (size_t)NNODES * 64 * 2);
    unsigned short* A3h = (unsigned short*)B1;                                    // A3 split, 25.6 MB each
    unsigned short* A3l = (unsigned short*)((char*)B1 + (size_t)NNODES * 256 * 2);
    unsigned short* Ah  = (unsigned short*)B1;                                    // A4 split, 12.8 MB each
    unsigned short* Al  = (unsigned short*)((char*)B1 + (size_t)NNODES * 128 * 2);

    const int* src = ei;
    const int* dst = ei + NEDGES;

    const int gN = (NNODES + 255) / 256;   // 196
    const int gE = (NEDGES + 255) / 256;

    k_init_cnt<<<gN, 256, 0, stream>>>(cnt);
    k_count<<<gE, 256, 0, stream>>>(dst, cnt);
    k_dinv<<<gN, 256, 0, stream>>>(cnt, dinv);
    k_bsum<<<gN, 256, 0, stream>>>(cnt, bsum);
    k_bscan<<<1, 256, 0, stream>>>(bsum, gN);
    k_rowptr<<<gN, 256, 0, stream>>>(cnt, bsum, rowptr);
    k_fill<<<gE, 256, 0, stream>>>(src, dst, rowptr, cnt, dinv, col, val);
    // weight splits for the MFMA decoder (no pipeline deps; tiny)
    k_wsplit<<<(128 * 1024 + 255) / 256, 256, 0, stream>>>(dWf, Wfh, Wfl, 128, 1024);
    k_wsplit<<<(64 * 256 + 255) / 256, 256, 0, stream>>>(dW1, W1h, W1l, 64, 256);
    k_wsplit<<<(256 * 128 + 255) / 256, 256, 0, stream>>>(dW2, W2h, W2l, 256, 128);

    const int MB = (NNODES + 127) / 128;     // 391 row-blocks
    const int MBP = ((MB + 7) / 8) * 8;      // 392, padded for XCD-pinned grid

    // ---- Encoder (fp32 GEMMs; aggregation inputs stored fp16) ----
    // H1 = x @ eW1 -> B1 as fp16 [50000,128] (12.8 MB; sole consumer = A1 agg)
    k_gemm<128,128,16,8,8,false,false,true><<<MB, 256, 0, stream>>>(x, eW1, nullptr, B1, NNODES, 128, 128, 1);
    // A1 = relu(agg(H1) + eb1) -> B2 fp32   (16B-lane fp16 gathers, CV=16)
    k_spmm<128,true,true,false><<<(NNODES * 16 + 255) / 256, 256, 0, stream>>>((const _Float16*)B1, dinv, rowptr, col, val, eb1, B2, nullptr, nullptr);
    // H2 = A1 @ eW2 -> B1 as fp16 [50000,64]
    k_gemm<128,64,16,8,4,false,false,true><<<MB, 256, 0, stream>>>(B2, eW2, nullptr, B1, NNODES, 64, 128, 1);
    // A2 = agg(H2) + eb2 -> B2 fp32         (CV=8)
    k_spmm<64,false,true,false><<<(NNODES * 8 + 255) / 256, 256, 0, stream>>>((const _Float16*)B1, dinv, rowptr, col, val, eb2, B2, nullptr, nullptr);
    // Z = A2 @ eWf + ebf -> B1 as fp16 [50000,64]
    k_gemm<128,64,16,8,4,false,false,true><<<MB, 256, 0, stream>>>(B2, eWf, ebf, B1, NNODES, 64, 64, 1);

    // ---- Decoder (MFMA bf16-split path) ----
    // G = agg(Z), bf16-split -> Gh/Gl in B2 (A2 dead; CV=8)
    k_spmm<64,false,false,true><<<(NNODES * 8 + 255) / 256, 256, 0, stream>>>((const _Float16*)B1, dinv, rowptr, col, val, nullptr, nullptr, Gh, Gl);
    // A3 = relu(G @ dW1 + db1), bf16-split -> A3h/A3l in B1 (Z dead)  [K=64, N=256]
    k_mfma<64,true,true,false,false,false><<<MB * 2, 256, 0, stream>>>(Gh, Gl, W1h, W1l, db1, nullptr, A3h, A3l, NNODES, 256);
    // H4 = A3 @ dW2 -> B2 as fp16 [50000,128] (G dead)  [K=256, N=128]
    k_mfma<256,false,false,false,false,true><<<MB, 256, 0, stream>>>(A3h, A3l, W2h, W2l, nullptr, B2, nullptr, nullptr, NNODES, 128);
    // A4 = agg(H4) + db2, bf16-split -> Ah/Al in B1 (A3 dead; CV=16)
    k_spmm<128,false,true,true><<<(NNODES * 16 + 255) / 256, 256, 0, stream>>>((const _Float16*)B2, dinv, rowptr, col, val, db2, nullptr, Ah, Al);
    // x_hat = A4 @ dWf + dbf -> d_out  [K=128, N=1024]  (XCD-pinned grid,
    // nontemporal stores; B2 region of out fully overwritten after last read)
    k_mfma<128,false,false,true,true,false><<<MBP * 8, 256, 0, stream>>>(Ah, Al, Wfh, Wfl, dbf, out, nullptr, nullptr, NNODES, 1024);
}